// Round 1
// baseline (943.940 us; speedup 1.0000x reference)
//
#include <hip/hip_runtime.h>

typedef __bf16 bf8 __attribute__((ext_vector_type(8)));
typedef float f32x4 __attribute__((ext_vector_type(4)));

#define T_TOK 2048
#define HDIM 1024
#define IDIM 4096
#define NE 8
#define TM 64
#define BK 32
#define CAP 4608   // 4096 slots + 8 experts * 64 pad
#define MT_MAX 72  // worst-case padded M tiles (<= 4544/64 = 71)

__device__ __forceinline__ float gelu_tanh(float x) {
  float u = 0.7978845608028654f * (x + 0.044715f * x * x * x);
  float t = 1.0f - 2.0f / (1.0f + __expf(2.0f * u));  // tanh(u)
  return 0.5f * x * (1.0f + t);
}

// ---------------- router: one wave per token ----------------
__global__ __launch_bounds__(64) void router_kernel(
    const float* __restrict__ x, const float* __restrict__ Wg,
    float* __restrict__ logits_out, int* __restrict__ sel, float* __restrict__ wts)
{
  const int t = blockIdx.x;
  const int lane = threadIdx.x;
  float acc[NE];
#pragma unroll
  for (int e = 0; e < NE; ++e) acc[e] = 0.f;
  const float* xr = x + (size_t)t * HDIM;
  for (int h = lane; h < HDIM; h += 64) {
    float xv = xr[h];
    const float* wg = Wg + h * NE;
#pragma unroll
    for (int e = 0; e < NE; ++e) acc[e] += xv * wg[e];
  }
#pragma unroll
  for (int off = 32; off > 0; off >>= 1) {
#pragma unroll
    for (int e = 0; e < NE; ++e) acc[e] += __shfl_down(acc[e], off);
  }
  if (lane == 0) {
    float* lo = logits_out + (size_t)t * NE;
#pragma unroll
    for (int e = 0; e < NE; ++e) lo[e] = acc[e];
    // top-2, first-index-wins on ties (matches jax.lax.top_k)
    int i0 = 0; float v0 = acc[0];
#pragma unroll
    for (int e = 1; e < NE; ++e) if (acc[e] > v0) { v0 = acc[e]; i0 = e; }
    int i1 = -1; float v1 = -3.4e38f;
#pragma unroll
    for (int e = 0; e < NE; ++e) {
      if (e != i0 && acc[e] > v1) { v1 = acc[e]; i1 = e; }
    }
    float ex = __expf(v1 - v0);           // <= 1, stable
    float w0 = 1.0f / (1.0f + ex);
    sel[2 * t] = i0; sel[2 * t + 1] = i1;
    wts[2 * t] = w0; wts[2 * t + 1] = 1.0f - w0;
  }
}

// ---------------- build per-expert slot groups (1 block) ----------------
__global__ __launch_bounds__(256) void build_groups(
    const int* __restrict__ sel, const float* __restrict__ wts,
    int* __restrict__ slot_map, float* __restrict__ slot_w, int* __restrict__ meta)
{
  __shared__ int cnt[NE], cur[NE], offp[NE + 1];
  const int tid = threadIdx.x;
  if (tid < NE) { cnt[tid] = 0; cur[tid] = 0; }
  __syncthreads();
  for (int t = tid; t < T_TOK; t += 256) {
    atomicAdd(&cnt[sel[2 * t]], 1);
    atomicAdd(&cnt[sel[2 * t + 1]], 1);
  }
  __syncthreads();
  if (tid == 0) {
    int o = 0;
    for (int e = 0; e < NE; ++e) { offp[e] = o; o += ((cnt[e] + TM - 1) / TM) * TM; }
    offp[NE] = o;
    for (int e = 0; e <= NE; ++e) meta[e] = offp[e];
    meta[NE + 1] = o;  // padded total
  }
  __syncthreads();
  for (int p = tid; p < CAP; p += 256) { slot_map[p] = 0; slot_w[p] = 0.f; }
  __syncthreads();
  for (int t = tid; t < T_TOK; t += 256) {
#pragma unroll
    for (int k = 0; k < 2; ++k) {
      int e = sel[2 * t + k];
      int pos = offp[e] + atomicAdd(&cur[e], 1);
      slot_map[pos] = t;
      slot_w[pos] = wts[2 * t + k];
    }
  }
}

// ---------------- grouped GEMM1 + GLU: act = gelu(x@Win)*(x@Wv)*w ----------------
__global__ __launch_bounds__(256) void moe_mlp1(
    const float* __restrict__ x, const float* __restrict__ Win, const float* __restrict__ Wv,
    const int* __restrict__ slot_map, const float* __restrict__ slot_w,
    const int* __restrict__ meta, __bf16* __restrict__ act)
{
  const int total = meta[NE + 1];
  const int tm = blockIdx.x;
  const int base = tm * TM;
  if (base >= total) return;
  const int tn = blockIdx.y;

  int e = 0;
#pragma unroll
  for (int j = 1; j < NE; ++j) if (base >= meta[j]) e = j;

  __shared__ __align__(16) __bf16 As[TM][BK + 8];       // [m][k], pad to 40
  __shared__ __align__(16) __bf16 Bs[2][TM][BK + 8];    // [mat][n][k], transposed
  __shared__ int tok_s[TM];

  const int tid = threadIdx.x;
  if (tid < TM) tok_s[tid] = slot_map[base + tid];

  const float* WinE = Win + (size_t)e * HDIM * IDIM + (size_t)tn * TM;
  const float* WvE  = Wv  + (size_t)e * HDIM * IDIM + (size_t)tn * TM;

  const int lane = tid & 63, wave = tid >> 6;
  const int m16 = lane & 15, q = lane >> 4;
  const int ms = wave * 16;

  f32x4 accg[4], accv[4];
#pragma unroll
  for (int ns = 0; ns < 4; ++ns)
#pragma unroll
    for (int r = 0; r < 4; ++r) { accg[ns][r] = 0.f; accv[ns][r] = 0.f; }

  for (int k0 = 0; k0 < HDIM; k0 += BK) {
    __syncthreads();  // previous compute done; also makes tok_s visible on iter 0
    // A tile: 64 rows x 32 k fp32 -> bf16
#pragma unroll
    for (int rep = 0; rep < 2; ++rep) {
      int j = tid + rep * 256;              // 0..511
      int row = j >> 3, c4 = j & 7;
      int tok = tok_s[row];
      float4 f = *((const float4*)(x + (size_t)tok * HDIM + k0) + c4);
      __bf16* dst = &As[row][c4 * 4];
      dst[0] = (__bf16)f.x; dst[1] = (__bf16)f.y;
      dst[2] = (__bf16)f.z; dst[3] = (__bf16)f.w;
    }
    // B tiles: 32 k x 64 n fp32, transposed store -> [n][k]
#pragma unroll
    for (int mat = 0; mat < 2; ++mat) {
      const float* W = mat ? WvE : WinE;
#pragma unroll
      for (int rep = 0; rep < 2; ++rep) {
        int j = tid + rep * 256;
        int kk = j >> 4, n4 = (j & 15) * 4;
        float4 f = *((const float4*)(W + (size_t)(k0 + kk) * IDIM + n4));
        Bs[mat][n4 + 0][kk] = (__bf16)f.x;
        Bs[mat][n4 + 1][kk] = (__bf16)f.y;
        Bs[mat][n4 + 2][kk] = (__bf16)f.z;
        Bs[mat][n4 + 3][kk] = (__bf16)f.w;
      }
    }
    __syncthreads();
    bf8 a = *(const bf8*)&As[ms + m16][q * 8];
#pragma unroll
    for (int ns = 0; ns < 4; ++ns) {
      bf8 b0 = *(const bf8*)&Bs[0][ns * 16 + m16][q * 8];
      accg[ns] = __builtin_amdgcn_mfma_f32_16x16x32_bf16(a, b0, accg[ns], 0, 0, 0);
      bf8 b1 = *(const bf8*)&Bs[1][ns * 16 + m16][q * 8];
      accv[ns] = __builtin_amdgcn_mfma_f32_16x16x32_bf16(a, b1, accv[ns], 0, 0, 0);
    }
  }

  const int col0 = tn * TM + m16;
#pragma unroll
  for (int r = 0; r < 4; ++r) {
    int row = ms + q * 4 + r;
    int slot = base + row;
    float w = slot_w[slot];                 // 0 for pad slots -> act row = 0
    __bf16* arow = act + (size_t)slot * IDIM + col0;
#pragma unroll
    for (int ns = 0; ns < 4; ++ns) {
      float g = accg[ns][r], v = accv[ns][r];
      arow[ns * 16] = (__bf16)(gelu_tanh(g) * v * w);
    }
  }
}

// ---------------- grouped GEMM2 + scatter: out += act @ Wout[e] ----------------
__global__ __launch_bounds__(256) void moe_mlp2(
    const __bf16* __restrict__ act, const float* __restrict__ Wout,
    const int* __restrict__ slot_map, const int* __restrict__ meta,
    float* __restrict__ out)
{
  const int total = meta[NE + 1];
  const int tm = blockIdx.x;
  const int base = tm * TM;
  if (base >= total) return;
  const int tn = blockIdx.y;  // over H, 16 tiles

  int e = 0;
#pragma unroll
  for (int j = 1; j < NE; ++j) if (base >= meta[j]) e = j;

  __shared__ __align__(16) __bf16 As[TM][BK + 8];
  __shared__ __align__(16) __bf16 Bs[TM][BK + 8];
  __shared__ int tok_s[TM];

  const int tid = threadIdx.x;
  if (tid < TM) tok_s[tid] = slot_map[base + tid];

  const float* WoE = Wout + (size_t)e * IDIM * HDIM + (size_t)tn * TM;

  const int lane = tid & 63, wave = tid >> 6;
  const int m16 = lane & 15, q = lane >> 4;
  const int ms = wave * 16;

  f32x4 acc[4];
#pragma unroll
  for (int ns = 0; ns < 4; ++ns)
#pragma unroll
    for (int r = 0; r < 4; ++r) acc[ns][r] = 0.f;

  for (int k0 = 0; k0 < IDIM; k0 += BK) {
    __syncthreads();
    // A tile: 64 rows x 32 bf16, direct 16B copies
    {
      int row = tid >> 2, c = tid & 3;
      int slot = base + row;
      bf8 v = *(const bf8*)(act + (size_t)slot * IDIM + k0 + c * 8);
      *(bf8*)&As[row][c * 8] = v;
    }
    // B tile: 32 k x 64 n fp32, transposed store
#pragma unroll
    for (int rep = 0; rep < 2; ++rep) {
      int j = tid + rep * 256;
      int kk = j >> 4, n4 = (j & 15) * 4;
      float4 f = *((const float4*)(WoE + (size_t)(k0 + kk) * HDIM + n4));
      Bs[n4 + 0][kk] = (__bf16)f.x;
      Bs[n4 + 1][kk] = (__bf16)f.y;
      Bs[n4 + 2][kk] = (__bf16)f.z;
      Bs[n4 + 3][kk] = (__bf16)f.w;
    }
    __syncthreads();
    bf8 a = *(const bf8*)&As[ms + m16][q * 8];
#pragma unroll
    for (int ns = 0; ns < 4; ++ns) {
      bf8 b = *(const bf8*)&Bs[ns * 16 + m16][q * 8];
      acc[ns] = __builtin_amdgcn_mfma_f32_16x16x32_bf16(a, b, acc[ns], 0, 0, 0);
    }
  }

  const int col0 = tn * TM + m16;
#pragma unroll
  for (int r = 0; r < 4; ++r) {
    int row = ms + q * 4 + r;
    int tok = tok_s[row];                   // pad slots: tok 0, acc 0 -> adds 0
    float* orow = out + (size_t)tok * HDIM + col0;
#pragma unroll
    for (int ns = 0; ns < 4; ++ns) {
      atomicAdd(&orow[ns * 16], acc[ns][r]);
    }
  }
}

extern "C" void kernel_launch(void* const* d_in, const int* in_sizes, int n_in,
                              void* d_out, int out_size, void* d_ws, size_t ws_size,
                              hipStream_t stream) {
  const float* x    = (const float*)d_in[0];
  const float* Wg   = (const float*)d_in[1];
  const float* Win  = (const float*)d_in[2];
  const float* Wv   = (const float*)d_in[3];
  const float* Wout = (const float*)d_in[4];
  float* out = (float*)d_out;
  float* logits_out = out + (size_t)T_TOK * HDIM;

  // workspace layout (4-byte units from base)
  int*   sel      = (int*)d_ws;                       // [4096]
  float* wts      = (float*)d_ws + 4096;              // [4096]
  int*   slot_map = (int*)d_ws + 8192;                // [4608]
  float* slot_w   = (float*)d_ws + 8192 + 4608;       // [4608]
  int*   meta     = (int*)d_ws + 8192 + 9216;         // [16]
  __bf16* act     = (__bf16*)((char*)d_ws + 128 * 1024);  // [4608 * 4096] bf16 (~37.7 MB)

  hipMemsetAsync(d_out, 0, (size_t)out_size * sizeof(float), stream);
  router_kernel<<<T_TOK, 64, 0, stream>>>(x, Wg, logits_out, sel, wts);
  build_groups<<<1, 256, 0, stream>>>(sel, wts, slot_map, slot_w, meta);
  moe_mlp1<<<dim3(MT_MAX, IDIM / TM), 256, 0, stream>>>(x, Win, Wv, slot_map, slot_w, meta, act);
  moe_mlp2<<<dim3(MT_MAX, HDIM / TM), 256, 0, stream>>>(act, Wout, slot_map, meta, out);
}

// Round 2
// 697.256 us; speedup vs baseline: 1.3538x; 1.3538x over previous
//
#include <hip/hip_runtime.h>

typedef __bf16 bf8 __attribute__((ext_vector_type(8)));
typedef float f32x4 __attribute__((ext_vector_type(4)));

#define T_TOK 2048
#define HDIM 1024
#define IDIM 4096
#define NE 8
#define TM 128
#define TN 64
#define BK 32
#define CAP 5120   // 4096 slots + 8 experts * 128 pad
#define MT_MAX 40  // ceil((4096 + 8*127)/128)

__device__ __forceinline__ float gelu_tanh(float x) {
  float u = 0.7978845608028654f * (x + 0.044715f * x * x * x);
  float t = 1.0f - 2.0f / (1.0f + __expf(2.0f * u));  // tanh(u)
  return 0.5f * x * (1.0f + t);
}

__device__ __forceinline__ unsigned pk(float a, float b) {
  __bf16 x = (__bf16)a, y = (__bf16)b;
  unsigned short ux = __builtin_bit_cast(unsigned short, x);
  unsigned short uy = __builtin_bit_cast(unsigned short, y);
  return (unsigned)ux | ((unsigned)uy << 16);
}

// ---------------- router: one wave per token ----------------
__global__ __launch_bounds__(64) void router_kernel(
    const float* __restrict__ x, const float* __restrict__ Wg,
    float* __restrict__ logits_out, int* __restrict__ sel, float* __restrict__ wts)
{
  const int t = blockIdx.x;
  const int lane = threadIdx.x;
  float acc[NE];
#pragma unroll
  for (int e = 0; e < NE; ++e) acc[e] = 0.f;
  const float* xr = x + (size_t)t * HDIM;
  for (int h = lane; h < HDIM; h += 64) {
    float xv = xr[h];
    const float* wg = Wg + h * NE;
#pragma unroll
    for (int e = 0; e < NE; ++e) acc[e] += xv * wg[e];
  }
#pragma unroll
  for (int off = 32; off > 0; off >>= 1) {
#pragma unroll
    for (int e = 0; e < NE; ++e) acc[e] += __shfl_down(acc[e], off);
  }
  if (lane == 0) {
    float* lo = logits_out + (size_t)t * NE;
#pragma unroll
    for (int e = 0; e < NE; ++e) lo[e] = acc[e];
    int i0 = 0; float v0 = acc[0];
#pragma unroll
    for (int e = 1; e < NE; ++e) if (acc[e] > v0) { v0 = acc[e]; i0 = e; }
    int i1 = -1; float v1 = -3.4e38f;
#pragma unroll
    for (int e = 0; e < NE; ++e) {
      if (e != i0 && acc[e] > v1) { v1 = acc[e]; i1 = e; }
    }
    float ex = __expf(v1 - v0);
    float w0 = 1.0f / (1.0f + ex);
    sel[2 * t] = i0; sel[2 * t + 1] = i1;
    wts[2 * t] = w0; wts[2 * t + 1] = 1.0f - w0;
  }
}

// ---------------- build per-expert slot groups (1 block) ----------------
__global__ __launch_bounds__(256) void build_groups(
    const int* __restrict__ sel, const float* __restrict__ wts,
    int* __restrict__ slot_map, float* __restrict__ slot_w, int* __restrict__ meta)
{
  __shared__ int cnt[NE], cur[NE], offp[NE + 1];
  const int tid = threadIdx.x;
  if (tid < NE) { cnt[tid] = 0; cur[tid] = 0; }
  __syncthreads();
  for (int t = tid; t < T_TOK; t += 256) {
    atomicAdd(&cnt[sel[2 * t]], 1);
    atomicAdd(&cnt[sel[2 * t + 1]], 1);
  }
  __syncthreads();
  if (tid == 0) {
    int o = 0;
    for (int e = 0; e < NE; ++e) { offp[e] = o; o += ((cnt[e] + TM - 1) / TM) * TM; }
    offp[NE] = o;
    for (int e = 0; e <= NE; ++e) meta[e] = offp[e];
    meta[NE + 1] = o;
  }
  __syncthreads();
  for (int p = tid; p < CAP; p += 256) { slot_map[p] = 0; slot_w[p] = 0.f; }
  __syncthreads();
  for (int t = tid; t < T_TOK; t += 256) {
#pragma unroll
    for (int k = 0; k < 2; ++k) {
      int e = sel[2 * t + k];
      int pos = offp[e] + atomicAdd(&cur[e], 1);
      slot_map[pos] = t;
      slot_w[pos] = wts[2 * t + k];
    }
  }
}

// ---------------- grouped GEMM1 + GLU: act = gelu(x@Win)*(x@Wv)*w ----------------
// LDS layout: rows stride 40 bf16 (80B). B stored transposed with k-pair dword
// packing + column swizzle col=(k2+4*((n>>3)&3))&15 -> conflict-free b32 stores,
// 16B-aligned b128 fragment reads.
__global__ __launch_bounds__(256) void moe_mlp1(
    const float* __restrict__ x, const float* __restrict__ Win, const float* __restrict__ Wv,
    const int* __restrict__ slot_map, const float* __restrict__ slot_w,
    const int* __restrict__ meta, __bf16* __restrict__ act)
{
  const int total = meta[NE + 1];
  const int bid = blockIdx.x;
  const int tm = bid % MT_MAX, tn = bid / MT_MAX;
  const int base = tm * TM;
  if (base >= total) return;

  int e = 0;
#pragma unroll
  for (int j = 1; j < NE; ++j) if (base >= meta[j]) e = j;

  __shared__ __align__(16) __bf16 As[TM][40];       // 10240 B
  __shared__ __align__(16) __bf16 Bs[2][TN][40];    // 10240 B
  __shared__ int tok_s[TM];
  __shared__ float w_s[TM];

  const int tid = threadIdx.x;
  if (tid < TM) { tok_s[tid] = slot_map[base + tid]; w_s[tid] = slot_w[base + tid]; }

  const int bn = tn * TN;
  const float* WinE = Win + (size_t)e * HDIM * IDIM + bn;
  const float* WvE  = Wv  + (size_t)e * HDIM * IDIM + bn;

  const int lane = tid & 63, wave = tid >> 6;
  const int m16 = lane & 15, q = lane >> 4;
  const int mhalf = (wave & 1) * 64;     // 64 rows per wave (4 m-frags)
  const int nhalf = (wave >> 1) * 32;    // 32 cols per wave (2 n-frags per mat)

  // staging maps (k0-invariant)
  const int c4 = tid & 7, rowA0 = tid >> 3;          // A: 4 reps, rows +32
  const int n4 = (tid & 15) * 4, k2 = tid >> 4;      // B: 16 k-pair cols x 16 n-groups
  int offB[4];
#pragma unroll
  for (int i = 0; i < 4; ++i) {
    int n = n4 + i;
    offB[i] = n * 20 + ((k2 + 4 * ((n >> 3) & 3)) & 15);
  }

  f32x4 acc[2][2][4];  // [mat][ns][f]
#pragma unroll
  for (int mt = 0; mt < 2; ++mt)
#pragma unroll
    for (int ns = 0; ns < 2; ++ns)
#pragma unroll
      for (int f = 0; f < 4; ++f)
#pragma unroll
        for (int r = 0; r < 4; ++r) acc[mt][ns][f][r] = 0.f;

  for (int k0 = 0; k0 < HDIM; k0 += BK) {
    __syncthreads();
    // A tile: 128x32 fp32 -> bf16, row-contiguous dword-pair stores
#pragma unroll
    for (int rep = 0; rep < 4; ++rep) {
      int row = rowA0 + rep * 32;
      int tok = tok_s[row];
      float4 f = *((const float4*)(x + (size_t)tok * HDIM + k0) + c4);
      unsigned w0 = pk(f.x, f.y), w1 = pk(f.z, f.w);
      unsigned* dst = (unsigned*)((char*)As + row * 80 + c4 * 8);
      dst[0] = w0; dst[1] = w1;
    }
    // B tiles: 32k x 64n fp32, transposed k-pair-packed swizzled stores
#pragma unroll
    for (int mt = 0; mt < 2; ++mt) {
      const float* W = mt ? WvE : WinE;
      const float* r0 = W + (size_t)(k0 + 2 * k2) * IDIM + n4;
      float4 f0 = *(const float4*)r0;
      float4 f1 = *(const float4*)(r0 + IDIM);
      unsigned* BsW = (unsigned*)Bs[mt];
      BsW[offB[0]] = pk(f0.x, f1.x);
      BsW[offB[1]] = pk(f0.y, f1.y);
      BsW[offB[2]] = pk(f0.z, f1.z);
      BsW[offB[3]] = pk(f0.w, f1.w);
    }
    __syncthreads();

    bf8 a[4];
#pragma unroll
    for (int f = 0; f < 4; ++f)
      a[f] = *(const bf8*)((const char*)As + (mhalf + f * 16 + m16) * 80 + q * 16);
#pragma unroll
    for (int mt = 0; mt < 2; ++mt) {
#pragma unroll
      for (int ns = 0; ns < 2; ++ns) {
        int n = nhalf + ns * 16 + m16;
        int s = (n >> 3) & 3;
        bf8 b = *(const bf8*)((const char*)Bs[mt] + n * 80 + ((q + s) & 3) * 16);
#pragma unroll
        for (int f = 0; f < 4; ++f)
          acc[mt][ns][f] = __builtin_amdgcn_mfma_f32_16x16x32_bf16(a[f], b, acc[mt][ns][f], 0, 0, 0);
      }
    }
  }

  const int col0 = bn + nhalf + m16;
#pragma unroll
  for (int f = 0; f < 4; ++f) {
#pragma unroll
    for (int r = 0; r < 4; ++r) {
      int row = mhalf + f * 16 + q * 4 + r;
      float w = w_s[row];
      __bf16* arow = act + (size_t)(base + row) * IDIM + col0;
#pragma unroll
      for (int ns = 0; ns < 2; ++ns) {
        float g = acc[0][ns][f][r], v = acc[1][ns][f][r];
        arow[ns * 16] = (__bf16)(gelu_tanh(g) * v * w);
      }
    }
  }
}

// ---------------- grouped GEMM2 + scatter: out += act @ Wout[e] ----------------
__global__ __launch_bounds__(256) void moe_mlp2(
    const __bf16* __restrict__ act, const float* __restrict__ Wout,
    const int* __restrict__ slot_map, const int* __restrict__ meta,
    float* __restrict__ out)
{
  const int total = meta[NE + 1];
  const int bid = blockIdx.x;
  const int tm = bid % MT_MAX, tn = bid / MT_MAX;
  const int base = tm * TM;
  if (base >= total) return;

  int e = 0;
#pragma unroll
  for (int j = 1; j < NE; ++j) if (base >= meta[j]) e = j;

  __shared__ __align__(16) __bf16 As[TM][40];
  __shared__ __align__(16) __bf16 Bs[TN][40];
  __shared__ int tok_s[TM];

  const int tid = threadIdx.x;
  if (tid < TM) tok_s[tid] = slot_map[base + tid];

  const int bn = tn * TN;
  const float* WoE = Wout + (size_t)e * IDIM * HDIM + bn;

  const int lane = tid & 63, wave = tid >> 6;
  const int m16 = lane & 15, q = lane >> 4;
  const int mhalf = (wave & 1) * 64;
  const int nhalf = (wave >> 1) * 32;

  const int cA = tid & 3, rowA0 = tid >> 2;          // A: 2 reps, rows +64
  const int n4 = (tid & 15) * 4, k2 = tid >> 4;
  int offB[4];
#pragma unroll
  for (int i = 0; i < 4; ++i) {
    int n = n4 + i;
    offB[i] = n * 20 + ((k2 + 4 * ((n >> 3) & 3)) & 15);
  }

  f32x4 acc[2][4];  // [ns][f]
#pragma unroll
  for (int ns = 0; ns < 2; ++ns)
#pragma unroll
    for (int f = 0; f < 4; ++f)
#pragma unroll
      for (int r = 0; r < 4; ++r) acc[ns][f][r] = 0.f;

  for (int k0 = 0; k0 < IDIM; k0 += BK) {
    __syncthreads();
    // A tile: 128x32 bf16, direct b128 copies
#pragma unroll
    for (int rep = 0; rep < 2; ++rep) {
      int row = rowA0 + rep * 64;
      bf8 v = *(const bf8*)(act + (size_t)(base + row) * IDIM + k0 + cA * 8);
      *(bf8*)((char*)As + row * 80 + cA * 16) = v;
    }
    // B tile: 32k x 64n fp32, transposed k-pair-packed swizzled stores
    {
      const float* r0 = WoE + (size_t)(k0 + 2 * k2) * HDIM + n4;
      float4 f0 = *(const float4*)r0;
      float4 f1 = *(const float4*)(r0 + HDIM);
      unsigned* BsW = (unsigned*)Bs;
      BsW[offB[0]] = pk(f0.x, f1.x);
      BsW[offB[1]] = pk(f0.y, f1.y);
      BsW[offB[2]] = pk(f0.z, f1.z);
      BsW[offB[3]] = pk(f0.w, f1.w);
    }
    __syncthreads();

    bf8 a[4];
#pragma unroll
    for (int f = 0; f < 4; ++f)
      a[f] = *(const bf8*)((const char*)As + (mhalf + f * 16 + m16) * 80 + q * 16);
#pragma unroll
    for (int ns = 0; ns < 2; ++ns) {
      int n = nhalf + ns * 16 + m16;
      int s = (n >> 3) & 3;
      bf8 b = *(const bf8*)((const char*)Bs + n * 80 + ((q + s) & 3) * 16);
#pragma unroll
      for (int f = 0; f < 4; ++f)
        acc[ns][f] = __builtin_amdgcn_mfma_f32_16x16x32_bf16(a[f], b, acc[ns][f], 0, 0, 0);
    }
  }

  const int col0 = bn + nhalf + m16;
#pragma unroll
  for (int f = 0; f < 4; ++f) {
#pragma unroll
    for (int r = 0; r < 4; ++r) {
      int row = mhalf + f * 16 + q * 4 + r;
      int tok = tok_s[row];
      float* orow = out + (size_t)tok * HDIM + col0;
#pragma unroll
      for (int ns = 0; ns < 2; ++ns)
        atomicAdd(&orow[ns * 16], acc[ns][f][r]);
    }
  }
}

extern "C" void kernel_launch(void* const* d_in, const int* in_sizes, int n_in,
                              void* d_out, int out_size, void* d_ws, size_t ws_size,
                              hipStream_t stream) {
  const float* x    = (const float*)d_in[0];
  const float* Wg   = (const float*)d_in[1];
  const float* Win  = (const float*)d_in[2];
  const float* Wv   = (const float*)d_in[3];
  const float* Wout = (const float*)d_in[4];
  float* out = (float*)d_out;
  float* logits_out = out + (size_t)T_TOK * HDIM;

  int*   sel      = (int*)d_ws;                        // [4096]
  float* wts      = (float*)d_ws + 4096;               // [4096]
  int*   slot_map = (int*)d_ws + 8192;                 // [5120]
  float* slot_w   = (float*)d_ws + 8192 + 5120;        // [5120]
  int*   meta     = (int*)d_ws + 8192 + 10240;         // [16]
  __bf16* act     = (__bf16*)((char*)d_ws + 128 * 1024);  // [5120 * 4096] bf16 (~42 MB)

  hipMemsetAsync(d_out, 0, (size_t)out_size * sizeof(float), stream);
  router_kernel<<<T_TOK, 64, 0, stream>>>(x, Wg, logits_out, sel, wts);
  build_groups<<<1, 256, 0, stream>>>(sel, wts, slot_map, slot_w, meta);
  // 1-D grids, tm-fastest: consecutive blocks share the same B panel (L2/L3 reuse)
  moe_mlp1<<<MT_MAX * (IDIM / TN), 256, 0, stream>>>(x, Win, Wv, slot_map, slot_w, meta, act);
  moe_mlp2<<<MT_MAX * (HDIM / TN), 256, 0, stream>>>(act, Wout, slot_map, meta, out);
}

// Round 3
// 677.592 us; speedup vs baseline: 1.3931x; 1.0290x over previous
//
#include <hip/hip_runtime.h>
#include <stdint.h>

typedef __bf16 bf8 __attribute__((ext_vector_type(8)));
typedef float f32x4 __attribute__((ext_vector_type(4)));

#define T_TOK 2048
#define HDIM 1024
#define IDIM 4096
#define NE 8
#define TM 128
#define TN 64
#define BK 64
#define CAP 5120   // 4096 + 8*128 pad
#define MT_MAX 40

__device__ __forceinline__ float gelu_tanh(float x) {
  float u = 0.7978845608028654f * (x + 0.044715f * x * x * x);
  float t = 1.0f - 2.0f / (1.0f + __expf(2.0f * u));  // tanh(u)
  return 0.5f * x * (1.0f + t);
}

__device__ __forceinline__ uint32_t pk(float a, float b) {
  __bf16 x = (__bf16)a, y = (__bf16)b;
  unsigned short ux = __builtin_bit_cast(unsigned short, x);
  unsigned short uy = __builtin_bit_cast(unsigned short, y);
  return (uint32_t)ux | ((uint32_t)uy << 16);
}

// async global->LDS DMA, 16B per lane. Global addr per-lane; LDS dest must be
// wave-uniform base + lane*16 (m104/m108).
__device__ __forceinline__ void gl2lds16(const void* g, void* l) {
  __builtin_amdgcn_global_load_lds((const __attribute__((address_space(1))) uint32_t*)g,
                                   (__attribute__((address_space(3))) uint32_t*)l, 16, 0, 0);
}

// ---------------- router: one wave per token ----------------
__global__ __launch_bounds__(64) void router_kernel(
    const float* __restrict__ x, const float* __restrict__ Wg,
    float* __restrict__ logits_out, int* __restrict__ sel, float* __restrict__ wts)
{
  const int t = blockIdx.x;
  const int lane = threadIdx.x;
  float acc[NE];
#pragma unroll
  for (int e = 0; e < NE; ++e) acc[e] = 0.f;
  const float* xr = x + (size_t)t * HDIM;
  for (int h = lane; h < HDIM; h += 64) {
    float xv = xr[h];
    const float* wg = Wg + h * NE;
#pragma unroll
    for (int e = 0; e < NE; ++e) acc[e] += xv * wg[e];
  }
#pragma unroll
  for (int off = 32; off > 0; off >>= 1) {
#pragma unroll
    for (int e = 0; e < NE; ++e) acc[e] += __shfl_down(acc[e], off);
  }
  if (lane == 0) {
    float* lo = logits_out + (size_t)t * NE;
#pragma unroll
    for (int e = 0; e < NE; ++e) lo[e] = acc[e];
    int i0 = 0; float v0 = acc[0];
#pragma unroll
    for (int e = 1; e < NE; ++e) if (acc[e] > v0) { v0 = acc[e]; i0 = e; }
    int i1 = -1; float v1 = -3.4e38f;
#pragma unroll
    for (int e = 0; e < NE; ++e) {
      if (e != i0 && acc[e] > v1) { v1 = acc[e]; i1 = e; }
    }
    float ex = __expf(v1 - v0);
    float w0 = 1.0f / (1.0f + ex);
    sel[2 * t] = i0; sel[2 * t + 1] = i1;
    wts[2 * t] = w0; wts[2 * t + 1] = 1.0f - w0;
  }
}

// ---------------- build per-expert slot groups (1 block) ----------------
__global__ __launch_bounds__(256) void build_groups(
    const int* __restrict__ sel, const float* __restrict__ wts,
    int* __restrict__ slot_map, float* __restrict__ slot_w, int* __restrict__ meta)
{
  __shared__ int cnt[NE], cur[NE], offp[NE + 1];
  const int tid = threadIdx.x;
  if (tid < NE) { cnt[tid] = 0; cur[tid] = 0; }
  __syncthreads();
  for (int t = tid; t < T_TOK; t += 256) {
    atomicAdd(&cnt[sel[2 * t]], 1);
    atomicAdd(&cnt[sel[2 * t + 1]], 1);
  }
  __syncthreads();
  if (tid == 0) {
    int o = 0;
    for (int e = 0; e < NE; ++e) { offp[e] = o; o += ((cnt[e] + TM - 1) / TM) * TM; }
    offp[NE] = o;
    for (int e = 0; e <= NE; ++e) meta[e] = offp[e];
    meta[NE + 1] = o;
  }
  __syncthreads();
  for (int p = tid; p < CAP; p += 256) { slot_map[p] = 0; slot_w[p] = 0.f; }
  __syncthreads();
  for (int t = tid; t < T_TOK; t += 256) {
#pragma unroll
    for (int k = 0; k < 2; ++k) {
      int e = sel[2 * t + k];
      int pos = offp[e] + atomicAdd(&cur[e], 1);
      slot_map[pos] = t;
      slot_w[pos] = wts[2 * t + k];
    }
  }
}

// ---------------- prep: fp32->bf16 convert (+transpose for weights) ----------------
// src [K][N] fp32 -> dst [N][K] bf16, 32k x 64n tiles. k-pair dword packing +
// the round-2-proven column swizzle -> 2-way-max LDS conflicts (free).
template <int K, int N>
__device__ __forceinline__ void transpose_tile(const float* __restrict__ src,
                                               __bf16* __restrict__ dst,
                                               int kt, int nt, uint32_t* lds)
{
  const int tid = threadIdx.x;
  const int k0 = kt * 32, n0 = nt * 64;
  {
    const int n4 = (tid & 15) * 4, k2 = tid >> 4;
    const float* r0 = src + (size_t)(k0 + 2 * k2) * N + n0 + n4;
    float4 f0 = *(const float4*)r0;
    float4 f1 = *(const float4*)(r0 + N);
    float a0[4] = {f0.x, f0.y, f0.z, f0.w};
    float a1[4] = {f1.x, f1.y, f1.z, f1.w};
#pragma unroll
    for (int i = 0; i < 4; ++i) {
      int n = n4 + i;
      lds[n * 20 + ((k2 + 4 * ((n >> 3) & 3)) & 15)] = pk(a0[i], a1[i]);
    }
  }
  __syncthreads();
  {
    const int n = tid >> 2, c = tid & 3;
    const int s3 = (n >> 3) & 3;
    uint4 v = *(const uint4*)&lds[n * 20 + ((c + s3) & 3) * 4];
    *(uint4*)(dst + (size_t)(n0 + n) * K + k0 + c * 8) = v;
  }
}

__global__ __launch_bounds__(256) void prep_kernel(
    const float* __restrict__ x, const float* __restrict__ Win,
    const float* __restrict__ Wv, const float* __restrict__ Wout,
    __bf16* __restrict__ xbf, __bf16* __restrict__ WinT,
    __bf16* __restrict__ WvT, __bf16* __restrict__ WoutT)
{
  __shared__ uint32_t lds[64 * 20];
  const int b = blockIdx.x;
  if (b < 16384) {
    const int t = b & 2047, e = b >> 11;
    transpose_tile<HDIM, IDIM>(Win + (size_t)e * HDIM * IDIM,
                               WinT + (size_t)e * IDIM * HDIM, t & 31, t >> 5, lds);
  } else if (b < 32768) {
    const int t = b & 2047, e = (b - 16384) >> 11;
    transpose_tile<HDIM, IDIM>(Wv + (size_t)e * HDIM * IDIM,
                               WvT + (size_t)e * IDIM * HDIM, t & 31, t >> 5, lds);
  } else if (b < 49152) {
    const int t = b & 2047, e = (b - 32768) >> 11;
    transpose_tile<IDIM, HDIM>(Wout + (size_t)e * IDIM * HDIM,
                               WoutT + (size_t)e * HDIM * IDIM, t & 127, t >> 7, lds);
  } else {
    const int row = b - 49152;
    const int tid = threadIdx.x;
    float4 f = *((const float4*)(x + (size_t)row * HDIM) + tid);
    uint2 w; w.x = pk(f.x, f.y); w.y = pk(f.z, f.w);
    *((uint2*)(xbf + (size_t)row * HDIM) + tid) = w;
  }
}

// ---------------- grouped GEMM1 + GLU (m97-style DMA staging) ----------------
// LDS tiles row stride 128B (no pad: DMA requirement); chunk position XOR-swizzled
// by row&7 so ds_read_b128 fragment reads land 2 rows / 4-bank-group (conflict-free).
__global__ __launch_bounds__(256) void moe_mlp1(
    const __bf16* __restrict__ xbf, const __bf16* __restrict__ WinT,
    const __bf16* __restrict__ WvT, const int* __restrict__ slot_map,
    const float* __restrict__ slot_w, const int* __restrict__ meta,
    __bf16* __restrict__ act)
{
  const int total = meta[NE + 1];
  const int bid = blockIdx.x;
  const int tm = bid % MT_MAX, tn = bid / MT_MAX;
  const int base = tm * TM;
  if (base >= total) return;

  int e = 0;
#pragma unroll
  for (int j = 1; j < NE; ++j) if (base >= meta[j]) e = j;

  __shared__ __align__(16) __bf16 As[TM * BK];   // 16 KB
  __shared__ __align__(16) __bf16 Bg[TN * BK];   // 8 KB
  __shared__ __align__(16) __bf16 Bv[TN * BK];   // 8 KB

  const int tid = threadIdx.x;
  const int lane = tid & 63, wave = tid >> 6;
  const int m16 = lane & 15, q = lane >> 4;
  const int lrow = lane >> 3, lchunk = lane & 7;
  const int bn = tn * TN;

  const char* pA[4]; char* lA[4];
#pragma unroll
  for (int i = 0; i < 4; ++i) {
    int r = wave * 32 + i * 8 + lrow;
    int tok = slot_map[base + r];
    int c = lchunk ^ (r & 7);
    pA[i] = (const char*)(xbf + (size_t)tok * HDIM) + c * 16;
    lA[i] = (char*)As + (wave * 32 + i * 8) * 128 + lane * 16;
  }
  const char* pG[2]; const char* pV[2]; char* lG[2]; char* lV[2];
  const size_t wbase = (size_t)e * IDIM * HDIM;
#pragma unroll
  for (int i = 0; i < 2; ++i) {
    int r = wave * 16 + i * 8 + lrow;
    int c = lchunk ^ (r & 7);
    size_t off = (wbase + (size_t)(bn + r) * HDIM) * 2 + c * 16;
    pG[i] = (const char*)WinT + off;
    pV[i] = (const char*)WvT + off;
    lG[i] = (char*)Bg + (wave * 16 + i * 8) * 128 + lane * 16;
    lV[i] = (char*)Bv + (wave * 16 + i * 8) * 128 + lane * 16;
  }

  const int mh = (wave & 1) * 64, nh = (wave >> 1) * 32;
  int aoff[2][4], boff[2][2];
#pragma unroll
  for (int s = 0; s < 2; ++s) {
    int qc = s * 4 + q;
#pragma unroll
    for (int f = 0; f < 4; ++f) {
      int r = mh + f * 16 + m16;
      aoff[s][f] = r * 128 + ((qc ^ (r & 7)) * 16);
    }
#pragma unroll
    for (int j = 0; j < 2; ++j) {
      int r = nh + j * 16 + m16;
      boff[s][j] = r * 128 + ((qc ^ (r & 7)) * 16);
    }
  }

  f32x4 acc[2][2][4];
#pragma unroll
  for (int mt = 0; mt < 2; ++mt)
#pragma unroll
    for (int j = 0; j < 2; ++j)
#pragma unroll
      for (int f = 0; f < 4; ++f)
#pragma unroll
        for (int r = 0; r < 4; ++r) acc[mt][j][f][r] = 0.f;

  for (int it = 0; it < HDIM / BK; ++it) {
    __syncthreads();
#pragma unroll
    for (int i = 0; i < 4; ++i) { gl2lds16(pA[i], lA[i]); pA[i] += BK * 2; }
#pragma unroll
    for (int i = 0; i < 2; ++i) { gl2lds16(pG[i], lG[i]); pG[i] += BK * 2; }
#pragma unroll
    for (int i = 0; i < 2; ++i) { gl2lds16(pV[i], lV[i]); pV[i] += BK * 2; }
    __syncthreads();
#pragma unroll
    for (int s = 0; s < 2; ++s) {
      bf8 a[4], g2[2], v2[2];
#pragma unroll
      for (int f = 0; f < 4; ++f)
        a[f] = *(const bf8*)((const char*)As + aoff[s][f]);
#pragma unroll
      for (int j = 0; j < 2; ++j) {
        g2[j] = *(const bf8*)((const char*)Bg + boff[s][j]);
        v2[j] = *(const bf8*)((const char*)Bv + boff[s][j]);
      }
#pragma unroll
      for (int j = 0; j < 2; ++j)
#pragma unroll
        for (int f = 0; f < 4; ++f) {
          acc[0][j][f] = __builtin_amdgcn_mfma_f32_16x16x32_bf16(a[f], g2[j], acc[0][j][f], 0, 0, 0);
          acc[1][j][f] = __builtin_amdgcn_mfma_f32_16x16x32_bf16(a[f], v2[j], acc[1][j][f], 0, 0, 0);
        }
    }
  }

  const int col0 = bn + nh + m16;
#pragma unroll
  for (int f = 0; f < 4; ++f)
#pragma unroll
    for (int r = 0; r < 4; ++r) {
      int row = mh + f * 16 + q * 4 + r;
      int slot = base + row;
      float w = slot_w[slot];
      __bf16* arow = act + (size_t)slot * IDIM + col0;
#pragma unroll
      for (int j = 0; j < 2; ++j)
        arow[j * 16] = (__bf16)(gelu_tanh(acc[0][j][f][r]) * acc[1][j][f][r] * w);
    }
}

// ---------------- grouped GEMM2 + scatter ----------------
__global__ __launch_bounds__(256) void moe_mlp2(
    const __bf16* __restrict__ act, const __bf16* __restrict__ WoutT,
    const int* __restrict__ slot_map, const int* __restrict__ meta,
    float* __restrict__ out)
{
  const int total = meta[NE + 1];
  const int bid = blockIdx.x;
  const int tm = bid % MT_MAX, tn = bid / MT_MAX;
  const int base = tm * TM;
  if (base >= total) return;

  int e = 0;
#pragma unroll
  for (int j = 1; j < NE; ++j) if (base >= meta[j]) e = j;

  __shared__ __align__(16) __bf16 As[TM * BK];   // 16 KB
  __shared__ __align__(16) __bf16 Bs[TN * BK];   // 8 KB

  const int tid = threadIdx.x;
  const int lane = tid & 63, wave = tid >> 6;
  const int m16 = lane & 15, q = lane >> 4;
  const int lrow = lane >> 3, lchunk = lane & 7;
  const int bn = tn * TN;

  const char* pA[4]; char* lA[4];
#pragma unroll
  for (int i = 0; i < 4; ++i) {
    int r = wave * 32 + i * 8 + lrow;
    int c = lchunk ^ (r & 7);
    pA[i] = (const char*)(act + (size_t)(base + r) * IDIM) + c * 16;
    lA[i] = (char*)As + (wave * 32 + i * 8) * 128 + lane * 16;
  }
  const char* pB[2]; char* lB[2];
  const size_t wbase = (size_t)e * HDIM * IDIM;
#pragma unroll
  for (int i = 0; i < 2; ++i) {
    int r = wave * 16 + i * 8 + lrow;
    int c = lchunk ^ (r & 7);
    pB[i] = (const char*)WoutT + (wbase + (size_t)(bn + r) * IDIM) * 2 + c * 16;
    lB[i] = (char*)Bs + (wave * 16 + i * 8) * 128 + lane * 16;
  }

  const int mh = (wave & 1) * 64, nh = (wave >> 1) * 32;
  int aoff[2][4], boff[2][2];
#pragma unroll
  for (int s = 0; s < 2; ++s) {
    int qc = s * 4 + q;
#pragma unroll
    for (int f = 0; f < 4; ++f) {
      int r = mh + f * 16 + m16;
      aoff[s][f] = r * 128 + ((qc ^ (r & 7)) * 16);
    }
#pragma unroll
    for (int j = 0; j < 2; ++j) {
      int r = nh + j * 16 + m16;
      boff[s][j] = r * 128 + ((qc ^ (r & 7)) * 16);
    }
  }

  f32x4 acc[2][4];
#pragma unroll
  for (int j = 0; j < 2; ++j)
#pragma unroll
    for (int f = 0; f < 4; ++f)
#pragma unroll
      for (int r = 0; r < 4; ++r) acc[j][f][r] = 0.f;

  for (int it = 0; it < IDIM / BK; ++it) {
    __syncthreads();
#pragma unroll
    for (int i = 0; i < 4; ++i) { gl2lds16(pA[i], lA[i]); pA[i] += BK * 2; }
#pragma unroll
    for (int i = 0; i < 2; ++i) { gl2lds16(pB[i], lB[i]); pB[i] += BK * 2; }
    __syncthreads();
#pragma unroll
    for (int s = 0; s < 2; ++s) {
      bf8 a[4], b2[2];
#pragma unroll
      for (int f = 0; f < 4; ++f)
        a[f] = *(const bf8*)((const char*)As + aoff[s][f]);
#pragma unroll
      for (int j = 0; j < 2; ++j)
        b2[j] = *(const bf8*)((const char*)Bs + boff[s][j]);
#pragma unroll
      for (int j = 0; j < 2; ++j)
#pragma unroll
        for (int f = 0; f < 4; ++f)
          acc[j][f] = __builtin_amdgcn_mfma_f32_16x16x32_bf16(a[f], b2[j], acc[j][f], 0, 0, 0);
    }
  }

  const int col0 = bn + nh + m16;
#pragma unroll
  for (int f = 0; f < 4; ++f)
#pragma unroll
    for (int r = 0; r < 4; ++r) {
      int row = mh + f * 16 + q * 4 + r;
      int tok = slot_map[base + row];   // pad slot: tok 0, acc 0 -> adds 0
      float* orow = out + (size_t)tok * HDIM + col0;
#pragma unroll
      for (int j = 0; j < 2; ++j)
        atomicAdd(&orow[j * 16], acc[j][f][r]);
    }
}

extern "C" void kernel_launch(void* const* d_in, const int* in_sizes, int n_in,
                              void* d_out, int out_size, void* d_ws, size_t ws_size,
                              hipStream_t stream) {
  const float* x    = (const float*)d_in[0];
  const float* Wg   = (const float*)d_in[1];
  const float* Win  = (const float*)d_in[2];
  const float* Wv   = (const float*)d_in[3];
  const float* Wout = (const float*)d_in[4];
  float* out = (float*)d_out;
  float* logits_out = out + (size_t)T_TOK * HDIM;

  char* ws = (char*)d_ws;
  int*   sel      = (int*)(ws);
  float* wts      = (float*)(ws + (16 << 10));
  int*   slot_map = (int*)(ws + (32 << 10));
  float* slot_w   = (float*)(ws + (52 << 10));
  int*   meta     = (int*)(ws + (72 << 10));
  __bf16* xbf   = (__bf16*)(ws + (1ull << 20));     // 4 MB
  __bf16* WinT  = (__bf16*)(ws + (8ull << 20));     // 64 MB
  __bf16* WvT   = (__bf16*)(ws + (72ull << 20));    // 64 MB
  __bf16* WoutT = (__bf16*)(ws + (136ull << 20));   // 64 MB
  __bf16* actb  = (__bf16*)(ws + (200ull << 20));   // 40 MB

  hipMemsetAsync(d_out, 0, (size_t)out_size * sizeof(float), stream);
  router_kernel<<<T_TOK, 64, 0, stream>>>(x, Wg, logits_out, sel, wts);
  build_groups<<<1, 256, 0, stream>>>(sel, wts, slot_map, slot_w, meta);
  prep_kernel<<<49152 + 2048, 256, 0, stream>>>(x, Win, Wv, Wout, xbf, WinT, WvT, WoutT);
  moe_mlp1<<<MT_MAX * (IDIM / TN), 256, 0, stream>>>(xbf, WinT, WvT, slot_map, slot_w, meta, actb);
  moe_mlp2<<<MT_MAX * (HDIM / TN), 256, 0, stream>>>(actb, WoutT, slot_map, meta, out);
}

// Round 4
// 611.527 us; speedup vs baseline: 1.5436x; 1.1080x over previous
//
#include <hip/hip_runtime.h>
#include <stdint.h>

typedef __bf16 bf8 __attribute__((ext_vector_type(8)));
typedef float f32x4 __attribute__((ext_vector_type(4)));

#define T_TOK 2048
#define HDIM 1024
#define IDIM 4096
#define NE 8
#define TM 128
#define TN 64
#define BK 64
#define CAP 5120   // 4096 + 8*128 pad
#define MT_MAX 40

__device__ __forceinline__ float gelu_tanh(float x) {
  float u = 0.7978845608028654f * (x + 0.044715f * x * x * x);
  float t = 1.0f - 2.0f / (1.0f + __expf(2.0f * u));  // tanh(u)
  return 0.5f * x * (1.0f + t);
}

__device__ __forceinline__ uint32_t pk(float a, float b) {
  __bf16 x = (__bf16)a, y = (__bf16)b;
  unsigned short ux = __builtin_bit_cast(unsigned short, x);
  unsigned short uy = __builtin_bit_cast(unsigned short, y);
  return (uint32_t)ux | ((uint32_t)uy << 16);
}

// async global->LDS DMA, 16B per lane. LDS dest must be wave-uniform base +
// lane*16 (m104/m108).
__device__ __forceinline__ void gl2lds16(const void* g, void* l) {
  __builtin_amdgcn_global_load_lds((const __attribute__((address_space(1))) uint32_t*)g,
                                   (__attribute__((address_space(3))) uint32_t*)l, 16, 0, 0);
}

// ---------------- router: one wave per token; also converts x -> bf16 ----------------
__global__ __launch_bounds__(64) void router_kernel(
    const float* __restrict__ x, const float* __restrict__ Wg,
    float* __restrict__ logits_out, int* __restrict__ sel, float* __restrict__ wts,
    __bf16* __restrict__ xbf)
{
  const int t = blockIdx.x;
  const int lane = threadIdx.x;
  float acc[NE];
#pragma unroll
  for (int e = 0; e < NE; ++e) acc[e] = 0.f;
  const float* xr = x + (size_t)t * HDIM;
  __bf16* xbr = xbf + (size_t)t * HDIM;
#pragma unroll
  for (int rep = 0; rep < 4; ++rep) {
    int hb = rep * 256 + lane * 4;
    float4 f = *(const float4*)(xr + hb);
    uint2 w; w.x = pk(f.x, f.y); w.y = pk(f.z, f.w);
    *(uint2*)(xbr + hb) = w;
    float fv[4] = {f.x, f.y, f.z, f.w};
#pragma unroll
    for (int i = 0; i < 4; ++i) {
      const float* wg = Wg + (size_t)(hb + i) * NE;
      float4 w0 = *(const float4*)wg;
      float4 w1 = *(const float4*)(wg + 4);
      acc[0] += fv[i] * w0.x; acc[1] += fv[i] * w0.y;
      acc[2] += fv[i] * w0.z; acc[3] += fv[i] * w0.w;
      acc[4] += fv[i] * w1.x; acc[5] += fv[i] * w1.y;
      acc[6] += fv[i] * w1.z; acc[7] += fv[i] * w1.w;
    }
  }
#pragma unroll
  for (int off = 32; off > 0; off >>= 1) {
#pragma unroll
    for (int e = 0; e < NE; ++e) acc[e] += __shfl_down(acc[e], off);
  }
  if (lane == 0) {
    float* lo = logits_out + (size_t)t * NE;
#pragma unroll
    for (int e = 0; e < NE; ++e) lo[e] = acc[e];
    int i0 = 0; float v0 = acc[0];
#pragma unroll
    for (int e = 1; e < NE; ++e) if (acc[e] > v0) { v0 = acc[e]; i0 = e; }
    int i1 = -1; float v1 = -3.4e38f;
#pragma unroll
    for (int e = 0; e < NE; ++e) {
      if (e != i0 && acc[e] > v1) { v1 = acc[e]; i1 = e; }
    }
    float ex = __expf(v1 - v0);
    float w0 = 1.0f / (1.0f + ex);
    sel[2 * t] = i0; sel[2 * t + 1] = i1;
    wts[2 * t] = w0; wts[2 * t + 1] = 1.0f - w0;
  }
}

// ---------------- build per-expert slot groups (1 block) ----------------
// pad slots get slot_map = -1 (skipped in mlp2 epilogue; clamped for staging)
__global__ __launch_bounds__(256) void build_groups(
    const int* __restrict__ sel, const float* __restrict__ wts,
    int* __restrict__ slot_map, float* __restrict__ slot_w, int* __restrict__ meta)
{
  __shared__ int cnt[NE], cur[NE], offp[NE + 1];
  const int tid = threadIdx.x;
  if (tid < NE) { cnt[tid] = 0; cur[tid] = 0; }
  __syncthreads();
  for (int t = tid; t < T_TOK; t += 256) {
    atomicAdd(&cnt[sel[2 * t]], 1);
    atomicAdd(&cnt[sel[2 * t + 1]], 1);
  }
  __syncthreads();
  if (tid == 0) {
    int o = 0;
    for (int e = 0; e < NE; ++e) { offp[e] = o; o += ((cnt[e] + TM - 1) / TM) * TM; }
    offp[NE] = o;
    for (int e = 0; e <= NE; ++e) meta[e] = offp[e];
    meta[NE + 1] = o;
  }
  __syncthreads();
  for (int p = tid; p < CAP; p += 256) { slot_map[p] = -1; slot_w[p] = 0.f; }
  __syncthreads();
  for (int t = tid; t < T_TOK; t += 256) {
#pragma unroll
    for (int k = 0; k < 2; ++k) {
      int e = sel[2 * t + k];
      int pos = offp[e] + atomicAdd(&cur[e], 1);
      slot_map[pos] = t;
      slot_w[pos] = wts[2 * t + k];
    }
  }
}

// ---------------- prep v2: fp32 [K][N] -> bf16 [N][K], 64k x 128n tiles ----------------
// LDS row = 40 dwords (32 k-pair dwords + 8 pad). k-quad b64 stores at
// XOR-swizzled 16B chunk (c ^ (n&7)) -> <=2-way conflicts; b128 reads conflict-free.
template <int K, int N>
__device__ __forceinline__ void transpose_tile64x128(const float* __restrict__ src,
                                                     __bf16* __restrict__ dst,
                                                     int kt, int nt, uint32_t* lds)
{
  const int tid = threadIdx.x;
  const int k0 = kt * 64, n0 = nt * 128;
#pragma unroll
  for (int rep = 0; rep < 2; ++rep) {
    int k4 = (tid >> 5) + rep * 8;        // k-quad index 0..15
    int nc = tid & 31;                    // float4 chunk along n
    const float* p = src + (size_t)(k0 + k4 * 4) * N + n0 + nc * 4;
    float4 f0 = *(const float4*)p;
    float4 f1 = *(const float4*)(p + N);
    float4 f2 = *(const float4*)(p + 2 * N);
    float4 f3 = *(const float4*)(p + 3 * N);
    float a0[4] = {f0.x, f0.y, f0.z, f0.w};
    float a1[4] = {f1.x, f1.y, f1.z, f1.w};
    float a2[4] = {f2.x, f2.y, f2.z, f2.w};
    float a3[4] = {f3.x, f3.y, f3.z, f3.w};
    const int c = k4 >> 1, h = k4 & 1;
#pragma unroll
    for (int i = 0; i < 4; ++i) {
      int n = nc * 4 + i;
      uint32_t* q = &lds[n * 40 + ((c ^ (n & 7)) << 2) + (h << 1)];
      q[0] = pk(a0[i], a1[i]);
      q[1] = pk(a2[i], a3[i]);
    }
  }
  __syncthreads();
#pragma unroll
  for (int rep = 0; rep < 4; ++rep) {
    int n = (tid >> 3) + rep * 32;
    int c = tid & 7;                      // 16B chunk along k (8 bf16)
    uint4 v = *(const uint4*)&lds[n * 40 + ((c ^ (n & 7)) << 2)];
    *(uint4*)(dst + (size_t)(n0 + n) * K + k0 + c * 8) = v;
  }
}

__global__ __launch_bounds__(256) void prep_kernel(
    const float* __restrict__ Win, const float* __restrict__ Wv,
    const float* __restrict__ Wout, __bf16* __restrict__ WinT,
    __bf16* __restrict__ WvT, __bf16* __restrict__ WoutT)
{
  __shared__ uint32_t lds[128 * 40];
  const int b = blockIdx.x;
  if (b < 4096) {
    const int e = b >> 9, t = b & 511;    // 16 kt x 32 nt
    transpose_tile64x128<HDIM, IDIM>(Win + (size_t)e * HDIM * IDIM,
                                     WinT + (size_t)e * IDIM * HDIM, t & 15, t >> 4, lds);
  } else if (b < 8192) {
    const int e = (b - 4096) >> 9, t = b & 511;
    transpose_tile64x128<HDIM, IDIM>(Wv + (size_t)e * HDIM * IDIM,
                                     WvT + (size_t)e * IDIM * HDIM, t & 15, t >> 4, lds);
  } else {
    const int e = (b - 8192) >> 9, t = b & 511;  // 64 kt x 8 nt
    transpose_tile64x128<IDIM, HDIM>(Wout + (size_t)e * IDIM * HDIM,
                                     WoutT + (size_t)e * HDIM * IDIM, t & 63, t >> 6, lds);
  }
}

// ---------------- grouped GEMM1 + GLU (m97-style DMA staging) ----------------
__global__ __launch_bounds__(256) void moe_mlp1(
    const __bf16* __restrict__ xbf, const __bf16* __restrict__ WinT,
    const __bf16* __restrict__ WvT, const int* __restrict__ slot_map,
    const float* __restrict__ slot_w, const int* __restrict__ meta,
    __bf16* __restrict__ act)
{
  const int total = meta[NE + 1];
  const int bid = blockIdx.x;
  const int tm = bid % MT_MAX, tn = bid / MT_MAX;
  const int base = tm * TM;
  if (base >= total) return;

  int e = 0;
#pragma unroll
  for (int j = 1; j < NE; ++j) if (base >= meta[j]) e = j;

  __shared__ __align__(16) __bf16 As[TM * BK];   // 16 KB
  __shared__ __align__(16) __bf16 Bg[TN * BK];   // 8 KB
  __shared__ __align__(16) __bf16 Bv[TN * BK];   // 8 KB

  const int tid = threadIdx.x;
  const int lane = tid & 63, wave = tid >> 6;
  const int m16 = lane & 15, q = lane >> 4;
  const int lrow = lane >> 3, lchunk = lane & 7;
  const int bn = tn * TN;

  const char* pA[4]; char* lA[4];
#pragma unroll
  for (int i = 0; i < 4; ++i) {
    int r = wave * 32 + i * 8 + lrow;
    int tok = slot_map[base + r];
    if (tok < 0) tok = 0;                 // pad: load any valid row (w=0 kills it)
    int c = lchunk ^ (r & 7);
    pA[i] = (const char*)(xbf + (size_t)tok * HDIM) + c * 16;
    lA[i] = (char*)As + (wave * 32 + i * 8) * 128 + lane * 16;
  }
  const char* pG[2]; const char* pV[2]; char* lG[2]; char* lV[2];
  const size_t wbase = (size_t)e * IDIM * HDIM;
#pragma unroll
  for (int i = 0; i < 2; ++i) {
    int r = wave * 16 + i * 8 + lrow;
    int c = lchunk ^ (r & 7);
    size_t off = (wbase + (size_t)(bn + r) * HDIM) * 2 + c * 16;
    pG[i] = (const char*)WinT + off;
    pV[i] = (const char*)WvT + off;
    lG[i] = (char*)Bg + (wave * 16 + i * 8) * 128 + lane * 16;
    lV[i] = (char*)Bv + (wave * 16 + i * 8) * 128 + lane * 16;
  }

  const int mh = (wave & 1) * 64, nh = (wave >> 1) * 32;
  int aoff[2][4], boff[2][2];
#pragma unroll
  for (int s = 0; s < 2; ++s) {
    int qc = s * 4 + q;
#pragma unroll
    for (int f = 0; f < 4; ++f) {
      int r = mh + f * 16 + m16;
      aoff[s][f] = r * 128 + ((qc ^ (r & 7)) * 16);
    }
#pragma unroll
    for (int j = 0; j < 2; ++j) {
      int r = nh + j * 16 + m16;
      boff[s][j] = r * 128 + ((qc ^ (r & 7)) * 16);
    }
  }

  f32x4 acc[2][2][4];
#pragma unroll
  for (int mt = 0; mt < 2; ++mt)
#pragma unroll
    for (int j = 0; j < 2; ++j)
#pragma unroll
      for (int f = 0; f < 4; ++f)
#pragma unroll
        for (int r = 0; r < 4; ++r) acc[mt][j][f][r] = 0.f;

  for (int it = 0; it < HDIM / BK; ++it) {
    __syncthreads();
#pragma unroll
    for (int i = 0; i < 4; ++i) { gl2lds16(pA[i], lA[i]); pA[i] += BK * 2; }
#pragma unroll
    for (int i = 0; i < 2; ++i) { gl2lds16(pG[i], lG[i]); pG[i] += BK * 2; }
#pragma unroll
    for (int i = 0; i < 2; ++i) { gl2lds16(pV[i], lV[i]); pV[i] += BK * 2; }
    __syncthreads();
#pragma unroll
    for (int s = 0; s < 2; ++s) {
      bf8 a[4], g2[2], v2[2];
#pragma unroll
      for (int f = 0; f < 4; ++f)
        a[f] = *(const bf8*)((const char*)As + aoff[s][f]);
#pragma unroll
      for (int j = 0; j < 2; ++j) {
        g2[j] = *(const bf8*)((const char*)Bg + boff[s][j]);
        v2[j] = *(const bf8*)((const char*)Bv + boff[s][j]);
      }
#pragma unroll
      for (int j = 0; j < 2; ++j)
#pragma unroll
        for (int f = 0; f < 4; ++f) {
          acc[0][j][f] = __builtin_amdgcn_mfma_f32_16x16x32_bf16(a[f], g2[j], acc[0][j][f], 0, 0, 0);
          acc[1][j][f] = __builtin_amdgcn_mfma_f32_16x16x32_bf16(a[f], v2[j], acc[1][j][f], 0, 0, 0);
        }
    }
  }

  const int col0 = bn + nh + m16;
#pragma unroll
  for (int f = 0; f < 4; ++f)
#pragma unroll
    for (int r = 0; r < 4; ++r) {
      int row = mh + f * 16 + q * 4 + r;
      int slot = base + row;
      float w = slot_w[slot];
      __bf16* arow = act + (size_t)slot * IDIM + col0;
#pragma unroll
      for (int j = 0; j < 2; ++j)
        arow[j * 16] = (__bf16)(gelu_tanh(acc[0][j][f][r]) * acc[1][j][f][r] * w);
    }
}

// ---------------- grouped GEMM2 + scatter ----------------
__global__ __launch_bounds__(256) void moe_mlp2(
    const __bf16* __restrict__ act, const __bf16* __restrict__ WoutT,
    const int* __restrict__ slot_map, const int* __restrict__ meta,
    float* __restrict__ out)
{
  const int total = meta[NE + 1];
  const int bid = blockIdx.x;
  const int tm = bid % MT_MAX, tn = bid / MT_MAX;
  const int base = tm * TM;
  if (base >= total) return;

  int e = 0;
#pragma unroll
  for (int j = 1; j < NE; ++j) if (base >= meta[j]) e = j;

  __shared__ __align__(16) __bf16 As[TM * BK];   // 16 KB
  __shared__ __align__(16) __bf16 Bs[TN * BK];   // 8 KB

  const int tid = threadIdx.x;
  const int lane = tid & 63, wave = tid >> 6;
  const int m16 = lane & 15, q = lane >> 4;
  const int lrow = lane >> 3, lchunk = lane & 7;
  const int bn = tn * TN;

  const char* pA[4]; char* lA[4];
#pragma unroll
  for (int i = 0; i < 4; ++i) {
    int r = wave * 32 + i * 8 + lrow;
    int c = lchunk ^ (r & 7);
    pA[i] = (const char*)(act + (size_t)(base + r) * IDIM) + c * 16;
    lA[i] = (char*)As + (wave * 32 + i * 8) * 128 + lane * 16;
  }
  const char* pB[2]; char* lB[2];
  const size_t wbase = (size_t)e * HDIM * IDIM;
#pragma unroll
  for (int i = 0; i < 2; ++i) {
    int r = wave * 16 + i * 8 + lrow;
    int c = lchunk ^ (r & 7);
    pB[i] = (const char*)WoutT + (wbase + (size_t)(bn + r) * IDIM) * 2 + c * 16;
    lB[i] = (char*)Bs + (wave * 16 + i * 8) * 128 + lane * 16;
  }

  const int mh = (wave & 1) * 64, nh = (wave >> 1) * 32;
  int aoff[2][4], boff[2][2];
#pragma unroll
  for (int s = 0; s < 2; ++s) {
    int qc = s * 4 + q;
#pragma unroll
    for (int f = 0; f < 4; ++f) {
      int r = mh + f * 16 + m16;
      aoff[s][f] = r * 128 + ((qc ^ (r & 7)) * 16);
    }
#pragma unroll
    for (int j = 0; j < 2; ++j) {
      int r = nh + j * 16 + m16;
      boff[s][j] = r * 128 + ((qc ^ (r & 7)) * 16);
    }
  }

  f32x4 acc[2][4];
#pragma unroll
  for (int j = 0; j < 2; ++j)
#pragma unroll
    for (int f = 0; f < 4; ++f)
#pragma unroll
      for (int r = 0; r < 4; ++r) acc[j][f][r] = 0.f;

  for (int it = 0; it < IDIM / BK; ++it) {
    __syncthreads();
#pragma unroll
    for (int i = 0; i < 4; ++i) { gl2lds16(pA[i], lA[i]); pA[i] += BK * 2; }
#pragma unroll
    for (int i = 0; i < 2; ++i) { gl2lds16(pB[i], lB[i]); pB[i] += BK * 2; }
    __syncthreads();
#pragma unroll
    for (int s = 0; s < 2; ++s) {
      bf8 a[4], b2[2];
#pragma unroll
      for (int f = 0; f < 4; ++f)
        a[f] = *(const bf8*)((const char*)As + aoff[s][f]);
#pragma unroll
      for (int j = 0; j < 2; ++j)
        b2[j] = *(const bf8*)((const char*)Bs + boff[s][j]);
#pragma unroll
      for (int j = 0; j < 2; ++j)
#pragma unroll
        for (int f = 0; f < 4; ++f)
          acc[j][f] = __builtin_amdgcn_mfma_f32_16x16x32_bf16(a[f], b2[j], acc[j][f], 0, 0, 0);
    }
  }

  const int col0 = bn + nh + m16;
#pragma unroll
  for (int f = 0; f < 4; ++f)
#pragma unroll
    for (int r = 0; r < 4; ++r) {
      int row = mh + f * 16 + q * 4 + r;
      int tok = slot_map[base + row];
      if (tok >= 0) {                     // skip pad slots (no junk atomics)
        float* orow = out + (size_t)tok * HDIM + col0;
#pragma unroll
        for (int j = 0; j < 2; ++j)
          atomicAdd(&orow[j * 16], acc[j][f][r]);
      }
    }
}

extern "C" void kernel_launch(void* const* d_in, const int* in_sizes, int n_in,
                              void* d_out, int out_size, void* d_ws, size_t ws_size,
                              hipStream_t stream) {
  const float* x    = (const float*)d_in[0];
  const float* Wg   = (const float*)d_in[1];
  const float* Win  = (const float*)d_in[2];
  const float* Wv   = (const float*)d_in[3];
  const float* Wout = (const float*)d_in[4];
  float* out = (float*)d_out;
  float* logits_out = out + (size_t)T_TOK * HDIM;

  char* ws = (char*)d_ws;
  int*   sel      = (int*)(ws);
  float* wts      = (float*)(ws + (16 << 10));
  int*   slot_map = (int*)(ws + (32 << 10));
  float* slot_w   = (float*)(ws + (52 << 10));
  int*   meta     = (int*)(ws + (72 << 10));
  __bf16* xbf   = (__bf16*)(ws + (1ull << 20));     // 4 MB
  __bf16* WinT  = (__bf16*)(ws + (8ull << 20));     // 64 MB
  __bf16* WvT   = (__bf16*)(ws + (72ull << 20));    // 64 MB
  __bf16* WoutT = (__bf16*)(ws + (136ull << 20));   // 64 MB
  __bf16* actb  = (__bf16*)(ws + (200ull << 20));   // 40 MB

  hipMemsetAsync(d_out, 0, (size_t)out_size * sizeof(float), stream);
  router_kernel<<<T_TOK, 64, 0, stream>>>(x, Wg, logits_out, sel, wts, xbf);
  build_groups<<<1, 256, 0, stream>>>(sel, wts, slot_map, slot_w, meta);
  prep_kernel<<<12288, 256, 0, stream>>>(Win, Wv, Wout, WinT, WvT, WoutT);
  moe_mlp1<<<MT_MAX * (IDIM / TN), 256, 0, stream>>>(xbf, WinT, WvT, slot_map, slot_w, meta, actb);
  moe_mlp2<<<MT_MAX * (HDIM / TN), 256, 0, stream>>>(actb, WoutT, slot_map, meta, out);
}